// Round 6
// baseline (417.806 us; speedup 1.0000x reference)
//
#include <hip/hip_runtime.h>
#include <cstdint>
#include <cstddef>

#define N_PTS 50000
#define H 16
#define CIN 256
#define C 256
#define CPG 32
#define CR 64

typedef short bf16x8 __attribute__((ext_vector_type(8)));
typedef float f32x4 __attribute__((ext_vector_type(4)));

__device__ __forceinline__ unsigned short f2bf(float f) {
    unsigned int u = __float_as_uint(f);
    u += 0x7fff + ((u >> 16) & 1);
    return (unsigned short)(u >> 16);
}
__device__ __forceinline__ float bf2f(unsigned short s) {
    return __uint_as_float(((unsigned int)s) << 16);
}

// ---------------------------------------------------------------------------
// Merged prep: [0,6250) convert s_feats->bf16; [6250,6346) pack Wq|Wk|Wv
// B-frags; [6346,6359) pack Wd2/Wa1/Wa2 B-frags.
//   frag(kt,nt): lane l holds B[kt*32+(l>>4)*8+j][nt*16+(l&15)], j=0..7
// ---------------------------------------------------------------------------
__global__ __launch_bounds__(256) void prep_all(
    const float* __restrict__ feats,
    const float* __restrict__ Wq, const float* __restrict__ Wk,
    const float* __restrict__ Wv,
    const float* __restrict__ Wd2, const float* __restrict__ Wa1,
    const float* __restrict__ Wa2,
    unsigned short* __restrict__ A_bf16,
    unsigned short* __restrict__ gemmFrags,
    unsigned short* __restrict__ attnFrags)
{
    int bid = blockIdx.x;
    if (bid < 6250) {
        size_t i = ((size_t)bid * 256 + threadIdx.x) * 8;
        float4 f0 = *(const float4*)&feats[i];
        float4 f1 = *(const float4*)&feats[i + 4];
        unsigned short t[8] = {f2bf(f0.x), f2bf(f0.y), f2bf(f0.z), f2bf(f0.w),
                               f2bf(f1.x), f2bf(f1.y), f2bf(f1.z), f2bf(f1.w)};
        *(bf16x8*)&A_bf16[i] = *(bf16x8*)t;
    } else if (bid < 6346) {
        int t = (bid - 6250) * 256 + threadIdx.x;   // 0..24575
        int lane = t & 63;
        int f = t >> 6;                              // kt*48 + ntg
        int ntg = f % 48;
        const float* W = ntg < 16 ? Wq : (ntg < 32 ? Wk : Wv);
        int colc = (ntg & 15) * 16 + (lane & 15);
        int row0 = (f / 48) * 32 + ((lane >> 4) << 3);
        unsigned short tmp[8];
        #pragma unroll
        for (int j = 0; j < 8; ++j) tmp[j] = f2bf(W[(size_t)(row0 + j) * 256 + colc]);
        *(bf16x8*)&gemmFrags[(size_t)t * 8] = *(bf16x8*)tmp;
    } else {
        int t = (bid - 6346) * 256 + threadIdx.x;
        if (t >= 3200) return;
        const float* W; int Nc, NT, loc, base;
        if (t < 2048)      { W = Wd2; Nc = 256; NT = 16; loc = t;        base = 0; }
        else if (t < 3072) { W = Wa1; Nc = 32;  NT = 2;  loc = t - 2048; base = 16384; }
        else               { W = Wa2; Nc = 32;  NT = 2;  loc = t - 3072; base = 24576; }
        int f = loc >> 6, lane = loc & 63;
        int kt = f / NT, nt = f - kt * NT;
        int colc = nt * 16 + (lane & 15);
        int row0 = kt * 32 + ((lane >> 4) << 3);
        unsigned short tmp[8];
        #pragma unroll
        for (int j = 0; j < 8; ++j) tmp[j] = f2bf(W[(size_t)(row0 + j) * Nc + colc]);
        *(bf16x8*)&attnFrags[(size_t)(base + loc * 8)] = *(bf16x8*)tmp;
    }
}

// ---------------------------------------------------------------------------
// QKV GEMM v3: double-buffered LDS staging, ONE barrier per kt, next-kt A
// prefetch overlaps MFMA. bx 0,1 = q (128 cols); bx 2..5 = kv panel (64 cols
// of k AND v) -> packed dword store k|v<<16, fully coalesced.
// Output bf16 [N][768]: [0..255]=q, [256+2c]=k[c], [257+2c]=v[c].
// ---------------------------------------------------------------------------
__global__ __launch_bounds__(256) void qkv_gemm_mfma(
    const unsigned short* __restrict__ A,       // [N][256] bf16
    const unsigned short* __restrict__ wfrags,
    const float* __restrict__ bq, const float* __restrict__ bk,
    const float* __restrict__ bv, unsigned short* __restrict__ out)
{
    __shared__ unsigned short s_a[2][128 * 40];  // stride 40 -> 2-way-free banks
    const int tid = threadIdx.x;
    const int lane = tid & 63, wave = tid >> 6;
    const int quad = lane >> 4, col16 = lane & 15;
    const int bx = blockIdx.x, by = blockIdx.y;

    f32x4 acc[2][8] = {};
    const int mrow = tid >> 1, half = tid & 1;
    const int gm = by * 128 + mrow;
    const bool valid = gm < N_PTS;
    const unsigned short* arow = &A[(size_t)gm * 256 + half * 16];

    // prologue: stage kt=0 into buf0
    {
        bf16x8 pa0 = {0,0,0,0,0,0,0,0}, pa1 = pa0;
        if (valid) { pa0 = *(const bf16x8*)arow; pa1 = *(const bf16x8*)(arow + 8); }
        *(bf16x8*)&s_a[0][mrow * 40 + half * 16]     = pa0;
        *(bf16x8*)&s_a[0][mrow * 40 + half * 16 + 8] = pa1;
    }

    #pragma unroll
    for (int kt = 0; kt < 8; ++kt) {
        // issue next-kt A loads (fly over this kt's MFMAs)
        bf16x8 na0 = {0,0,0,0,0,0,0,0}, na1 = na0;
        if (kt < 7 && valid) {
            const unsigned short* src = arow + (kt + 1) * 32;
            na0 = *(const bf16x8*)src;
            na1 = *(const bf16x8*)(src + 8);
        }
        __syncthreads();                         // buf[kt&1] ready for all
        const unsigned short* buf = s_a[kt & 1];
        bf16x8 af0 = *(const bf16x8*)&buf[(wave * 32 + col16) * 40 + quad * 8];
        bf16x8 af1 = *(const bf16x8*)&buf[(wave * 32 + 16 + col16) * 40 + quad * 8];
        #pragma unroll
        for (int nt = 0; nt < 8; ++nt) {
            int ntg = (bx < 2) ? (bx * 8 + nt)
                               : (nt < 4 ? 16 + (bx - 2) * 4 + nt
                                         : 32 + (bx - 2) * 4 + (nt - 4));
            bf16x8 bf = *(const bf16x8*)&wfrags[(((size_t)kt * 48 + ntg) * 64 + lane) * 8];
            acc[0][nt] = __builtin_amdgcn_mfma_f32_16x16x32_bf16(af0, bf, acc[0][nt], 0, 0, 0);
            acc[1][nt] = __builtin_amdgcn_mfma_f32_16x16x32_bf16(af1, bf, acc[1][nt], 0, 0, 0);
        }
        if (kt < 7) {                            // write buf[(kt+1)&1]; safe: last
            unsigned short* nbuf = s_a[(kt + 1) & 1];   // reads of it preceded this
            *(bf16x8*)&nbuf[mrow * 40 + half * 16]     = na0;  // iteration's barrier
            *(bf16x8*)&nbuf[mrow * 40 + half * 16 + 8] = na1;
        }
    }

    if (bx < 2) {
        #pragma unroll
        for (int nt = 0; nt < 8; ++nt) {
            int cIn = bx * 128 + nt * 16 + col16;
            float bb = bq[cIn];
            #pragma unroll
            for (int mt = 0; mt < 2; ++mt)
                #pragma unroll
                for (int r = 0; r < 4; ++r) {
                    int row = by * 128 + wave * 32 + mt * 16 + quad * 4 + r;
                    if (row < N_PTS)
                        out[(size_t)row * 768 + cIn] = f2bf(acc[mt][nt][r] + bb);
                }
        }
    } else {
        unsigned int* out32 = (unsigned int*)out;
        #pragma unroll
        for (int t = 0; t < 4; ++t) {
            int cIn = (bx - 2) * 64 + t * 16 + col16;
            float kb = bk[cIn], vb = bv[cIn];
            #pragma unroll
            for (int mt = 0; mt < 2; ++mt)
                #pragma unroll
                for (int r = 0; r < 4; ++r) {
                    int row = by * 128 + wave * 32 + mt * 16 + quad * 4 + r;
                    if (row < N_PTS) {
                        unsigned int kk = f2bf(acc[mt][t][r] + kb);
                        unsigned int vv = f2bf(acc[mt][t + 4][r] + vb);
                        out32[(size_t)row * 384 + 128 + cIn] = kk | (vv << 16);
                    }
                }
        }
    }
}

// ---------------------------------------------------------------------------
// Fused attention v4: 4 points/block. d1 for ALL 4 points computed up front
// (one amortized barrier); a2+softmax fused on wave 0; next point's gathers
// issued after the a1-sync. 3 barriers per point.
// ---------------------------------------------------------------------------
#define D1S 72
#define PGS 66      // private geom row stride (dwords)
#define QKS 264
#define A1S 40
#define A2S 33

__global__ __launch_bounds__(256, 3) void attn_mfma(
    const unsigned short* __restrict__ qkv,     // [N][768] q | kv-interleaved
    const float* __restrict__ q_pts, const float* __restrict__ s_pts,
    const int* __restrict__ nbr,
    const float* __restrict__ Wd1, const float* __restrict__ bd1,
    const float* __restrict__ bd2,
    const unsigned short* __restrict__ frags,
    const float* __restrict__ ba1, const float* __restrict__ ba2,
    float* __restrict__ out)
{
    __shared__ unsigned short s_d1a[4 * H * D1S];  // d1 for all 4 points
    __shared__ float          s_pg[4 * H * PGS];   // wave-private geom tiles
    __shared__ unsigned short s_qk[H * QKS];
    __shared__ unsigned short s_a1[H * A1S];
    __shared__ float          s_a2[H * A2S];
    __shared__ float          s_rel[4][H][3];
    __shared__ int            s_idx[4][H];

    const int tid = threadIdx.x;
    const int lane = tid & 63, wave = tid >> 6;
    const int quad = lane >> 4, col = lane & 15;
    const int n0 = blockIdx.x * 4;
    const int c = tid;                 // == wave*64 + lane

    if (tid < 64) {
        int pp = tid >> 4, hh = tid & 15;
        int idx = nbr[(size_t)(n0 + pp) * H + hh];
        s_idx[pp][hh] = idx;
        #pragma unroll
        for (int x = 0; x < 3; ++x)
            s_rel[pp][hh][x] = s_pts[(size_t)idx * 3 + x] - q_pts[(size_t)(n0 + pp) * 3 + x];
    }

    const float w1x = Wd1[lane], w1y = Wd1[64 + lane], w1z = Wd1[128 + lane];
    const float b1 = bd1[lane];
    const float b2 = bd2[c];
    bf16x8 wd2f[2][4];
    #pragma unroll
    for (int t = 0; t < 4; ++t) {
        wd2f[0][t] = *(const bf16x8*)&frags[((size_t)((0 * 16 + wave * 4 + t) * 64 + lane)) * 8];
        wd2f[1][t] = *(const bf16x8*)&frags[((size_t)((1 * 16 + wave * 4 + t) * 64 + lane)) * 8];
    }
    bf16x8 wa1f[8];
    bf16x8 wa2f[2] = {{0,0,0,0,0,0,0,0}, {0,0,0,0,0,0,0,0}};
    if (wave < 2) {
        #pragma unroll
        for (int kt = 0; kt < 8; ++kt)
            wa1f[kt] = *(const bf16x8*)&frags[16384 + ((size_t)((kt * 2 + wave) * 64 + lane)) * 8];
    }
    if (wave == 0) {
        wa2f[0] = *(const bf16x8*)&frags[24576 + ((size_t)(0 * 64 + lane)) * 8];
        wa2f[1] = *(const bf16x8*)&frags[24576 + ((size_t)(1 * 64 + lane)) * 8];
    }
    __syncthreads();

    // d1 for ALL 4 points: thread (wave,lane) -> r=lane, (p,h) = pass*4+wave
    #pragma unroll
    for (int pass = 0; pass < 16; ++pass) {
        int hp = pass * 4 + wave;          // p*16 + h
        int p = hp >> 4, h = hp & 15;
        float v = b1 + s_rel[p][h][0] * w1x + s_rel[p][h][1] * w1y + s_rel[p][h][2] * w1z;
        s_d1a[hp * D1S + lane] = f2bf(fmaxf(v, 0.1f * v));
    }
    __syncthreads();

    float* pg = &s_pg[wave * (H * PGS)];

    // issue point 0's gathers
    unsigned int u[H];
    #pragma unroll
    for (int h = 0; h < H; ++h)
        u[h] = *(const unsigned int*)&qkv[(size_t)s_idx[0][h] * 768 + 256 + 2 * c];
    float qf = bf2f(qkv[(size_t)s_idx[0][0] * 768 + c]);

    for (int p = 0; p < 4; ++p) {
        const int n = n0 + p;

        // geom = d1 @ Wd2 -> wave-private C-tile in LDS (no barrier)
        {
            const unsigned short* d1p = &s_d1a[p * H * D1S];
            bf16x8 ga = *(const bf16x8*)&d1p[col * D1S + quad * 8];
            bf16x8 gb = *(const bf16x8*)&d1p[col * D1S + 32 + quad * 8];
            #pragma unroll
            for (int t = 0; t < 4; ++t) {
                f32x4 acc = {0.f, 0.f, 0.f, 0.f};
                acc = __builtin_amdgcn_mfma_f32_16x16x32_bf16(ga, wd2f[0][t], acc, 0, 0, 0);
                acc = __builtin_amdgcn_mfma_f32_16x16x32_bf16(gb, wd2f[1][t], acc, 0, 0, 0);
                #pragma unroll
                for (int rr = 0; rr < 4; ++rr)
                    pg[(quad * 4 + rr) * PGS + t * 16 + col] = acc[rr];
            }
        }

        // consume gathers + private geom (same-wave ds, lgkmcnt only)
        float vg[H];
        #pragma unroll
        for (int h = 0; h < H; ++h) {
            float g = pg[h * PGS + lane] + b2;
            float nk = __uint_as_float(u[h] << 16);
            float nv = __uint_as_float(u[h] & 0xffff0000u);
            vg[h] = nv - g;
            float tq = qf - nk - g;
            s_qk[h * QKS + c] = f2bf(fmaxf(tq, 0.1f * tq));
        }
        __syncthreads();                        // qk-sync

        // a1 = lrelu(qk @ Wa1 + ba1) on waves 0,1
        if (wave < 2) {
            f32x4 acc = {0.f, 0.f, 0.f, 0.f};
            #pragma unroll
            for (int kt = 0; kt < 8; ++kt) {
                bf16x8 a = *(bf16x8*)&s_qk[col * QKS + kt * 32 + quad * 8];
                acc = __builtin_amdgcn_mfma_f32_16x16x32_bf16(a, wa1f[kt], acc, 0, 0, 0);
            }
            int j = wave * 16 + col;
            float bb = ba1[j];
            #pragma unroll
            for (int rr = 0; rr < 4; ++rr) {
                float v = acc[rr] + bb;
                s_a1[(quad * 4 + rr) * A1S + j] = f2bf(fmaxf(v, 0.1f * v));
            }
        }
        __syncthreads();                        // a1-sync

        // issue NEXT point's gathers: the final-sync drain overlaps softmax
        if (p < 3) {
            #pragma unroll
            for (int h = 0; h < H; ++h)
                u[h] = *(const unsigned int*)&qkv[(size_t)s_idx[p + 1][h] * 768 + 256 + 2 * c];
            qf = bf2f(qkv[(size_t)s_idx[p + 1][0] * 768 + c]);
        }

        // a2 + softmax fused on wave 0 (own ds writes -> reads, no barrier)
        if (wave == 0) {
            bf16x8 aa = *(bf16x8*)&s_a1[col * A1S + quad * 8];
            #pragma unroll
            for (int nt = 0; nt < 2; ++nt) {
                f32x4 acc = {0.f, 0.f, 0.f, 0.f};
                acc = __builtin_amdgcn_mfma_f32_16x16x32_bf16(aa, wa2f[nt], acc, 0, 0, 0);
                int j = nt * 16 + col;
                float bb = ba2[j];
                #pragma unroll
                for (int rr = 0; rr < 4; ++rr)
                    s_a2[(quad * 4 + rr) * A2S + j] = acc[rr] + bb;
            }
            int j = lane & 31, hb = (lane >> 5) * 8;
            float vals[8];
            float mx = -1e30f;
            #pragma unroll
            for (int i = 0; i < 8; ++i) {
                vals[i] = s_a2[(hb + i) * A2S + j];
                mx = fmaxf(mx, vals[i]);
            }
            mx = fmaxf(mx, __shfl_xor(mx, 32));
            float sum = 0.f;
            #pragma unroll
            for (int i = 0; i < 8; ++i) { vals[i] = __expf(vals[i] - mx); sum += vals[i]; }
            sum += __shfl_xor(sum, 32);
            float inv = 1.f / sum;
            #pragma unroll
            for (int i = 0; i < 8; ++i) s_a2[(hb + i) * A2S + j] = vals[i] * inv;
        }
        __syncthreads();                        // final-sync

        // out[n][c] = sum_h vg[h] * attn[h][c>>3]
        float o = 0.f;
        const int aj = c >> 3;
        #pragma unroll
        for (int h = 0; h < H; ++h) o += vg[h] * s_a2[h * A2S + aj];
        out[(size_t)n * C + c] = o;
    }
}

// ---------------------------------------------------------------------------

extern "C" void kernel_launch(void* const* d_in, const int* in_sizes, int n_in,
                              void* d_out, int out_size, void* d_ws, size_t ws_size,
                              hipStream_t stream) {
    const float* q_pts   = (const float*)d_in[0];
    const float* s_pts   = (const float*)d_in[1];
    const float* s_feats = (const float*)d_in[2];
    const int*   nbr     = (const int*)d_in[3];
    const float* Wq  = (const float*)d_in[4];
    const float* bq  = (const float*)d_in[5];
    const float* Wk  = (const float*)d_in[6];
    const float* bk  = (const float*)d_in[7];
    const float* Wv  = (const float*)d_in[8];
    const float* bv  = (const float*)d_in[9];
    const float* Wd1 = (const float*)d_in[10];
    const float* bd1 = (const float*)d_in[11];
    const float* Wd2 = (const float*)d_in[12];
    const float* bd2 = (const float*)d_in[13];
    const float* Wa1 = (const float*)d_in[14];
    const float* ba1 = (const float*)d_in[15];
    const float* Wa2 = (const float*)d_in[16];
    const float* ba2 = (const float*)d_in[17];

    float* out = (float*)d_out;
    char* ws = (char*)d_ws;
    unsigned short* A_bf16    = (unsigned short*)(ws);                 // 25.6 MB
    unsigned short* qkvb      = (unsigned short*)(ws + 25600000);      // 76.8 MB
    unsigned short* attnFrags = (unsigned short*)(ws + 102400000);     // 51.2 KB
    unsigned short* gemmFrags = (unsigned short*)(ws + 102451200);     // 384 KB

    prep_all<<<6359, 256, 0, stream>>>(s_feats, Wq, Wk, Wv, Wd2, Wa1, Wa2,
                                       A_bf16, gemmFrags, attnFrags);

    dim3 g1(6, (N_PTS + 127) / 128);
    qkv_gemm_mfma<<<g1, 256, 0, stream>>>(A_bf16, gemmFrags, bq, bk, bv, qkvb);

    attn_mfma<<<(N_PTS / 4), 256, 0, stream>>>(qkvb, q_pts, s_pts, nbr,
                                               Wd1, bd1, bd2, attnFrags,
                                               ba1, ba2, out);
}